// Round 1
// baseline (1436.971 us; speedup 1.0000x reference)
//
#include <hip/hip_runtime.h>

#define N_NODES 10000
#define N_EDGES 640000
#define D_FEAT 128

// ---------------------------------------------------------------------------
// Kernel 1: zero the aggregation buffer (we reuse d_out as agg storage;
// harness poisons it with 0xAA before every launch).
// ---------------------------------------------------------------------------
__global__ void zero_kernel(float4* __restrict__ agg4, int n4) {
    int i = blockIdx.x * blockDim.x + threadIdx.x;
    if (i < n4) agg4[i] = float4{0.f, 0.f, 0.f, 0.f};
}

// ---------------------------------------------------------------------------
// Kernel 2: scatter-add edge features into agg.
// 32 threads per edge, one float4 (16 B) per thread -> coalesced 512 B row
// reads. unsafeAtomicAdd emits hardware global_atomic_add_f32 (no CAS loop).
// ---------------------------------------------------------------------------
__global__ __launch_bounds__(256) void scatter_kernel(
        const float4* __restrict__ edge_feat4,
        const int* __restrict__ recv,
        float* __restrict__ agg) {
    long gid = (long)blockIdx.x * blockDim.x + threadIdx.x;
    int e  = (int)(gid >> 5);   // edge index
    int c4 = (int)(gid & 31);   // which float4 of the 128-float row
    if (e >= N_EDGES) return;
    int r = recv[e];
    float4 v = edge_feat4[(long)e * 32 + c4];
    float* dst = agg + (long)r * D_FEAT + c4 * 4;
    unsafeAtomicAdd(dst + 0, v.x);
    unsafeAtomicAdd(dst + 1, v.y);
    unsafeAtomicAdd(dst + 2, v.z);
    unsafeAtomicAdd(dst + 3, v.w);
}

// ---------------------------------------------------------------------------
// Kernel 3: out[n,:] = concat(node_feat[n,:], agg[n,:]) @ W + b
// Block = 128 threads (thread j = output column), NT=16 nodes per block.
// collected tile staged in LDS (16 KB); W loads are lane-coalesced and each
// loaded value is reused 16x (once per node) from registers.
// In-place safe: agg rows are fully read into LDS before out rows (the same
// addresses) are written, and each block touches only its own 16 rows.
// ---------------------------------------------------------------------------
#define NT 16
__global__ __launch_bounds__(128) void gemm_kernel(
        const float* __restrict__ node_feat,
        const float* __restrict__ agg,
        const float* __restrict__ W,
        const float* __restrict__ b,
        float* __restrict__ out) {
    __shared__ float coll[NT][2 * D_FEAT];   // 16 x 256 floats = 16 KB
    const int n0 = blockIdx.x * NT;
    const int j  = threadIdx.x;              // 0..127

    #pragma unroll
    for (int i = 0; i < NT; ++i) {
        coll[i][j]           = node_feat[(long)(n0 + i) * D_FEAT + j];
        coll[i][D_FEAT + j]  = agg[(long)(n0 + i) * D_FEAT + j];
    }
    __syncthreads();

    float acc[NT];
    const float bias = b[j];
    #pragma unroll
    for (int i = 0; i < NT; ++i) acc[i] = bias;

    for (int k = 0; k < 2 * D_FEAT; k += 4) {
        const float w0 = W[(long)(k + 0) * D_FEAT + j];
        const float w1 = W[(long)(k + 1) * D_FEAT + j];
        const float w2 = W[(long)(k + 2) * D_FEAT + j];
        const float w3 = W[(long)(k + 3) * D_FEAT + j];
        #pragma unroll
        for (int i = 0; i < NT; ++i) {
            float4 c = *(const float4*)&coll[i][k];  // LDS broadcast read
            acc[i] += c.x * w0 + c.y * w1 + c.z * w2 + c.w * w3;
        }
    }

    #pragma unroll
    for (int i = 0; i < NT; ++i)
        out[(long)(n0 + i) * D_FEAT + j] = acc[i];
}

// ---------------------------------------------------------------------------
extern "C" void kernel_launch(void* const* d_in, const int* in_sizes, int n_in,
                              void* d_out, int out_size, void* d_ws, size_t ws_size,
                              hipStream_t stream) {
    const float* edge_feat = (const float*)d_in[0];   // [640000,128] f32
    const float* node_feat = (const float*)d_in[1];   // [10000,128]  f32
    const int*   recv      = (const int*)d_in[2];     // [640000]     i32
    const float* W         = (const float*)d_in[3];   // [256,128]    f32
    const float* b         = (const float*)d_in[4];   // [128]        f32
    float* out = (float*)d_out;                       // [10000,128]  f32

    // agg lives in d_out; GEMM consumes it in-place.
    float* agg = out;

    const int n4 = N_NODES * D_FEAT / 4;              // 320000 float4s
    zero_kernel<<<(n4 + 255) / 256, 256, 0, stream>>>((float4*)agg, n4);

    const long scatter_threads = (long)N_EDGES * 32;  // 20.48M
    scatter_kernel<<<(int)(scatter_threads / 256), 256, 0, stream>>>(
        (const float4*)edge_feat, recv, agg);

    gemm_kernel<<<N_NODES / NT, 128, 0, stream>>>(node_feat, agg, W, b, out);
}

// Round 2
// 587.830 us; speedup vs baseline: 2.4445x; 2.4445x over previous
//
#include <hip/hip_runtime.h>

#define N_NODES 10000
#define N_EDGES 640000
#define D_FEAT 128

// ---------------------------------------------------------------------------
// ws layout (int32 offsets into d_ws):
//   counts  @ [0      , 10000)
//   start   @ [16384  , 16384+10001)   (exclusive prefix + total sentinel)
//   cursor  @ [32768  , 32768+10000)
//   sorted  @ [49152  , 49152+640000)
// total = 689152 ints = 2.76 MB
// ---------------------------------------------------------------------------
#define WS_COUNTS 0
#define WS_START  16384
#define WS_CURSOR 32768
#define WS_SORTED 49152
#define WS_INTS_NEEDED (WS_SORTED + N_EDGES)

__global__ void zero_counts_kernel(int* __restrict__ counts) {
    int i = blockIdx.x * blockDim.x + threadIdx.x;
    if (i < N_NODES) counts[i] = 0;
}

__global__ void hist_kernel(const int* __restrict__ recv, int* __restrict__ counts) {
    int e = blockIdx.x * blockDim.x + threadIdx.x;
    if (e < N_EDGES) atomicAdd(&counts[recv[e]], 1);
}

// Single-block exclusive prefix sum over 10000 counts -> start[] and cursor[].
__global__ __launch_bounds__(1024) void prefix_kernel(const int* __restrict__ counts,
                                                      int* __restrict__ start,
                                                      int* __restrict__ cursor) {
    __shared__ int buf[1024];
    __shared__ int carry;
    const int tid = threadIdx.x;
    if (tid == 0) carry = 0;
    __syncthreads();
    for (int base = 0; base < N_NODES; base += 1024) {
        const int c = carry;                  // snapshot before update
        const int idx = base + tid;
        const int v = (idx < N_NODES) ? counts[idx] : 0;
        buf[tid] = v;
        __syncthreads();
        // Hillis-Steele inclusive scan
        for (int off = 1; off < 1024; off <<= 1) {
            int t = (tid >= off) ? buf[tid - off] : 0;
            __syncthreads();
            buf[tid] += t;
            __syncthreads();
        }
        const int excl = buf[tid] - v + c;
        if (idx < N_NODES) { start[idx] = excl; cursor[idx] = excl; }
        __syncthreads();
        if (tid == 0) carry = c + buf[1023];
        __syncthreads();
    }
    if (tid == 0) start[N_NODES] = N_EDGES;
}

// Scatter edge IDs into per-node contiguous segments.
__global__ void reorder_kernel(const int* __restrict__ recv,
                               int* __restrict__ cursor,
                               int* __restrict__ sorted_eid) {
    int e = blockIdx.x * blockDim.x + threadIdx.x;
    if (e < N_EDGES) {
        int pos = atomicAdd(&cursor[recv[e]], 1);
        sorted_eid[pos] = e;
    }
}

// One block per node; thread j accumulates feature column j.
// Row reads are 512B-contiguous, fully coalesced. No atomics.
__global__ __launch_bounds__(128) void gather_kernel(
        const float* __restrict__ edge_feat,
        const int* __restrict__ sorted_eid,
        const int* __restrict__ start,
        float* __restrict__ agg) {
    const int n = blockIdx.x;
    const int j = threadIdx.x;
    const int s = start[n];
    const int e_end = start[n + 1];
    float acc = 0.f;
    int i = s;
    for (; i + 4 <= e_end; i += 4) {
        // 4 independent row loads in flight per thread
        const int e0 = sorted_eid[i + 0];
        const int e1 = sorted_eid[i + 1];
        const int e2 = sorted_eid[i + 2];
        const int e3 = sorted_eid[i + 3];
        const float v0 = edge_feat[(long)e0 * D_FEAT + j];
        const float v1 = edge_feat[(long)e1 * D_FEAT + j];
        const float v2 = edge_feat[(long)e2 * D_FEAT + j];
        const float v3 = edge_feat[(long)e3 * D_FEAT + j];
        acc += (v0 + v1) + (v2 + v3);
    }
    for (; i < e_end; ++i)
        acc += edge_feat[(long)sorted_eid[i] * D_FEAT + j];
    agg[(long)n * D_FEAT + j] = acc;
}

// ---------------------------------------------------------------------------
// Fallback path (ws too small): direct atomic scatter.
// ---------------------------------------------------------------------------
__global__ void zero_agg_kernel(float4* __restrict__ agg4, int n4) {
    int i = blockIdx.x * blockDim.x + threadIdx.x;
    if (i < n4) agg4[i] = float4{0.f, 0.f, 0.f, 0.f};
}

__global__ __launch_bounds__(256) void scatter_kernel(
        const float4* __restrict__ edge_feat4,
        const int* __restrict__ recv,
        float* __restrict__ agg) {
    long gid = (long)blockIdx.x * blockDim.x + threadIdx.x;
    int e  = (int)(gid >> 5);
    int c4 = (int)(gid & 31);
    if (e >= N_EDGES) return;
    int r = recv[e];
    float4 v = edge_feat4[(long)e * 32 + c4];
    float* dst = agg + (long)r * D_FEAT + c4 * 4;
    unsafeAtomicAdd(dst + 0, v.x);
    unsafeAtomicAdd(dst + 1, v.y);
    unsafeAtomicAdd(dst + 2, v.z);
    unsafeAtomicAdd(dst + 3, v.w);
}

// ---------------------------------------------------------------------------
// GEMM: out[n,:] = concat(node_feat[n,:], agg[n,:]) @ W + b
// In-place safe: agg rows (== out rows) fully staged in LDS before overwrite.
// ---------------------------------------------------------------------------
#define NT 16
__global__ __launch_bounds__(128) void gemm_kernel(
        const float* __restrict__ node_feat,
        const float* __restrict__ agg,
        const float* __restrict__ W,
        const float* __restrict__ b,
        float* __restrict__ out) {
    __shared__ float coll[NT][2 * D_FEAT];
    const int n0 = blockIdx.x * NT;
    const int j  = threadIdx.x;

    #pragma unroll
    for (int i = 0; i < NT; ++i) {
        coll[i][j]          = node_feat[(long)(n0 + i) * D_FEAT + j];
        coll[i][D_FEAT + j] = agg[(long)(n0 + i) * D_FEAT + j];
    }
    __syncthreads();

    float acc[NT];
    const float bias = b[j];
    #pragma unroll
    for (int i = 0; i < NT; ++i) acc[i] = bias;

    for (int k = 0; k < 2 * D_FEAT; k += 4) {
        const float w0 = W[(long)(k + 0) * D_FEAT + j];
        const float w1 = W[(long)(k + 1) * D_FEAT + j];
        const float w2 = W[(long)(k + 2) * D_FEAT + j];
        const float w3 = W[(long)(k + 3) * D_FEAT + j];
        #pragma unroll
        for (int i = 0; i < NT; ++i) {
            float4 c = *(const float4*)&coll[i][k];
            acc[i] += c.x * w0 + c.y * w1 + c.z * w2 + c.w * w3;
        }
    }

    #pragma unroll
    for (int i = 0; i < NT; ++i)
        out[(long)(n0 + i) * D_FEAT + j] = acc[i];
}

// ---------------------------------------------------------------------------
extern "C" void kernel_launch(void* const* d_in, const int* in_sizes, int n_in,
                              void* d_out, int out_size, void* d_ws, size_t ws_size,
                              hipStream_t stream) {
    const float* edge_feat = (const float*)d_in[0];
    const float* node_feat = (const float*)d_in[1];
    const int*   recv      = (const int*)d_in[2];
    const float* W         = (const float*)d_in[3];
    const float* b         = (const float*)d_in[4];
    float* out = (float*)d_out;
    float* agg = out;   // reuse output buffer for agg; GEMM consumes in-place

    if (ws_size >= (size_t)WS_INTS_NEEDED * sizeof(int)) {
        int* wsi    = (int*)d_ws;
        int* counts = wsi + WS_COUNTS;
        int* startp = wsi + WS_START;
        int* cursor = wsi + WS_CURSOR;
        int* sorted = wsi + WS_SORTED;

        zero_counts_kernel<<<(N_NODES + 255) / 256, 256, 0, stream>>>(counts);
        hist_kernel<<<(N_EDGES + 255) / 256, 256, 0, stream>>>(recv, counts);
        prefix_kernel<<<1, 1024, 0, stream>>>(counts, startp, cursor);
        reorder_kernel<<<(N_EDGES + 255) / 256, 256, 0, stream>>>(recv, cursor, sorted);
        gather_kernel<<<N_NODES, 128, 0, stream>>>(edge_feat, sorted, startp, agg);
    } else {
        // fallback: atomic scatter
        const int n4 = N_NODES * D_FEAT / 4;
        zero_agg_kernel<<<(n4 + 255) / 256, 256, 0, stream>>>((float4*)agg, n4);
        const long scatter_threads = (long)N_EDGES * 32;
        scatter_kernel<<<(int)(scatter_threads / 256), 256, 0, stream>>>(
            (const float4*)edge_feat, recv, agg);
    }

    gemm_kernel<<<N_NODES / NT, 128, 0, stream>>>(node_feat, agg, W, b, out);
}

// Round 3
// 577.885 us; speedup vs baseline: 2.4866x; 1.0172x over previous
//
#include <hip/hip_runtime.h>

#define N_NODES 10000
#define N_EDGES 640000
#define D_FEAT 128

// ---------------------------------------------------------------------------
// ws layout (int32 element offsets into d_ws):
//   counts  @ [0      , 10000)
//   start   @ [16384  , 16384+10001)   (exclusive prefix + total sentinel)
//   cursor  @ [32768  , 32768+10000)
//   sorted  @ [49152  , 49152+640000)
// ---------------------------------------------------------------------------
#define WS_COUNTS 0
#define WS_START  16384
#define WS_CURSOR 32768
#define WS_SORTED 49152
#define WS_INTS_NEEDED (WS_SORTED + N_EDGES)

__global__ void zero_counts_kernel(int* __restrict__ counts) {
    int i = blockIdx.x * blockDim.x + threadIdx.x;
    if (i < N_NODES) counts[i] = 0;
}

__global__ void hist_kernel(const int* __restrict__ recv, int* __restrict__ counts) {
    int e = blockIdx.x * blockDim.x + threadIdx.x;
    if (e < N_EDGES) atomicAdd(&counts[recv[e]], 1);
}

// ---------------------------------------------------------------------------
// Single-block exclusive prefix sum, wave-shuffle based (3 barriers/tile
// instead of Hillis-Steele's 20).
// ---------------------------------------------------------------------------
__global__ __launch_bounds__(1024) void prefix_kernel(const int* __restrict__ counts,
                                                      int* __restrict__ start,
                                                      int* __restrict__ cursor) {
    __shared__ int wsum[16];
    __shared__ int carry_s;
    const int tid  = threadIdx.x;
    const int lane = tid & 63;
    const int wave = tid >> 6;
    if (tid == 0) carry_s = 0;
    __syncthreads();
    for (int base = 0; base < N_NODES; base += 1024) {
        const int idx = base + tid;
        const int v = (idx < N_NODES) ? counts[idx] : 0;
        // inclusive scan within wave
        int x = v;
        #pragma unroll
        for (int off = 1; off < 64; off <<= 1) {
            int t = __shfl_up(x, off, 64);
            if (lane >= off) x += t;
        }
        if (lane == 63) wsum[wave] = x;
        __syncthreads();                       // B1
        if (wave == 0) {                       // scan the 16 wave sums
            int ws = (lane < 16) ? wsum[lane] : 0;
            #pragma unroll
            for (int off = 1; off < 16; off <<= 1) {
                int t = __shfl_up(ws, off, 64);
                if (lane >= off) ws += t;
            }
            if (lane < 16) wsum[lane] = ws;    // inclusive
        }
        __syncthreads();                       // B2
        const int carry   = carry_s;
        const int waveoff = (wave == 0) ? 0 : wsum[wave - 1];
        const int excl    = carry + waveoff + x - v;
        if (idx < N_NODES) { start[idx] = excl; cursor[idx] = excl; }
        __syncthreads();                       // B3
        if (tid == 1023) carry_s = carry + wsum[15];  // total of this tile
    }
    if (tid == 0) start[N_NODES] = N_EDGES;
}

// Scatter edge IDs into per-node contiguous segments.
__global__ void reorder_kernel(const int* __restrict__ recv,
                               int* __restrict__ cursor,
                               int* __restrict__ sorted_eid) {
    int e = blockIdx.x * blockDim.x + threadIdx.x;
    if (e < N_EDGES) {
        int pos = atomicAdd(&cursor[recv[e]], 1);
        sorted_eid[pos] = e;
    }
}

// ---------------------------------------------------------------------------
// Gather-sum: one 256-thread block per node. 8 row-reader groups (w) of 32
// lanes (l); lane l reads float4 column-chunk l of each row -> 16 B/lane,
// fully coalesced 512 B row reads, 8 rows in flight per block. Final
// cross-group reduce through LDS. No atomics.
// ---------------------------------------------------------------------------
#define GW 8
__global__ __launch_bounds__(256) void gather_kernel(
        const float4* __restrict__ edge_feat4,
        const int* __restrict__ sorted_eid,
        const int* __restrict__ start,
        float4* __restrict__ agg4) {
    __shared__ float4 red[GW][32];             // 16 KB
    const int n   = blockIdx.x;
    const int tid = threadIdx.x;
    const int l   = tid & 31;                  // float4 chunk (cols 4l..4l+3)
    const int w   = tid >> 5;                  // row-reader group
    const int s = start[n];
    const int e = start[n + 1];
    float4 acc = {0.f, 0.f, 0.f, 0.f};
    for (int i = s + w; i < e; i += GW) {
        const long eid = sorted_eid[i];
        const float4 v = edge_feat4[eid * 32 + l];
        acc.x += v.x; acc.y += v.y; acc.z += v.z; acc.w += v.w;
    }
    red[w][l] = acc;
    __syncthreads();
    if (w == 0) {
        float4 r = red[0][l];
        #pragma unroll
        for (int k = 1; k < GW; ++k) {
            const float4 t = red[k][l];
            r.x += t.x; r.y += t.y; r.z += t.z; r.w += t.w;
        }
        agg4[(long)n * 32 + l] = r;
    }
}

// ---------------------------------------------------------------------------
// GEMM: out[n,:] = concat(node_feat[n,:], agg[n,:]) @ W + b
// In-place safe: agg rows (== out rows) fully staged in LDS before overwrite.
// ---------------------------------------------------------------------------
#define NT 16
__global__ __launch_bounds__(128) void gemm_kernel(
        const float* __restrict__ node_feat,
        const float* __restrict__ agg,
        const float* __restrict__ W,
        const float* __restrict__ b,
        float* __restrict__ out) {
    __shared__ float coll[NT][2 * D_FEAT];     // 16 KB
    const int n0 = blockIdx.x * NT;
    const int j  = threadIdx.x;

    #pragma unroll
    for (int i = 0; i < NT; ++i) {
        coll[i][j]          = node_feat[(long)(n0 + i) * D_FEAT + j];
        coll[i][D_FEAT + j] = agg[(long)(n0 + i) * D_FEAT + j];
    }
    __syncthreads();

    float acc[NT];
    const float bias = b[j];
    #pragma unroll
    for (int i = 0; i < NT; ++i) acc[i] = bias;

    for (int k = 0; k < 2 * D_FEAT; k += 4) {
        const float w0 = W[(long)(k + 0) * D_FEAT + j];
        const float w1 = W[(long)(k + 1) * D_FEAT + j];
        const float w2 = W[(long)(k + 2) * D_FEAT + j];
        const float w3 = W[(long)(k + 3) * D_FEAT + j];
        #pragma unroll
        for (int i = 0; i < NT; ++i) {
            const float4 c = *(const float4*)&coll[i][k];
            acc[i] += c.x * w0 + c.y * w1 + c.z * w2 + c.w * w3;
        }
    }

    #pragma unroll
    for (int i = 0; i < NT; ++i)
        out[(long)(n0 + i) * D_FEAT + j] = acc[i];
}

// ---------------------------------------------------------------------------
extern "C" void kernel_launch(void* const* d_in, const int* in_sizes, int n_in,
                              void* d_out, int out_size, void* d_ws, size_t ws_size,
                              hipStream_t stream) {
    const float* edge_feat = (const float*)d_in[0];
    const float* node_feat = (const float*)d_in[1];
    const int*   recv      = (const int*)d_in[2];
    const float* W         = (const float*)d_in[3];
    const float* b         = (const float*)d_in[4];
    float* out = (float*)d_out;
    float* agg = out;   // reuse output buffer for agg; GEMM consumes in-place

    int* wsi    = (int*)d_ws;
    int* counts = wsi + WS_COUNTS;
    int* startp = wsi + WS_START;
    int* cursor = wsi + WS_CURSOR;
    int* sorted = wsi + WS_SORTED;

    zero_counts_kernel<<<(N_NODES + 255) / 256, 256, 0, stream>>>(counts);
    hist_kernel<<<(N_EDGES + 255) / 256, 256, 0, stream>>>(recv, counts);
    prefix_kernel<<<1, 1024, 0, stream>>>(counts, startp, cursor);
    reorder_kernel<<<(N_EDGES + 255) / 256, 256, 0, stream>>>(recv, cursor, sorted);
    gather_kernel<<<N_NODES, 256, 0, stream>>>(
        (const float4*)edge_feat, sorted, startp, (float4*)agg);
    gemm_kernel<<<N_NODES / NT, 128, 0, stream>>>(node_feat, agg, W, b, out);
}

// Round 4
// 552.336 us; speedup vs baseline: 2.6016x; 1.0463x over previous
//
#include <hip/hip_runtime.h>

#define N_NODES 10000
#define N_EDGES 640000
#define D_FEAT 128

// ---------------------------------------------------------------------------
// ws layout (int32 element offsets into d_ws):
//   counts @ [0, 10000)        bsum @ [10240, 10280)     boff @ [10304, 10344)
//   start  @ [16384, 26385)    cursor @ [32768, 42768)
//   sorted @ [49152, 689152)   agg   @ [689152, 1969152)  (float[10000][128])
// ---------------------------------------------------------------------------
#define WS_COUNTS 0
#define WS_BSUM   10240
#define WS_BOFF   10304
#define WS_START  16384
#define WS_CURSOR 32768
#define WS_SORTED 49152
#define WS_AGG    689152

#define NPB 40   // prefix blocks: ceil(10000/256)

__global__ void zero_counts_kernel(int* __restrict__ counts) {
    int i = blockIdx.x * blockDim.x + threadIdx.x;
    if (i < N_NODES) counts[i] = 0;
}

__global__ void hist_kernel(const int4* __restrict__ recv4, int* __restrict__ counts) {
    int i = blockIdx.x * blockDim.x + threadIdx.x;
    if (i < N_EDGES / 4) {
        const int4 r = recv4[i];
        atomicAdd(&counts[r.x], 1);
        atomicAdd(&counts[r.y], 1);
        atomicAdd(&counts[r.z], 1);
        atomicAdd(&counts[r.w], 1);
    }
}

// --- 3-phase exclusive scan over counts[10000] -> start[], cursor[] ---------
__global__ __launch_bounds__(256) void prefix1_kernel(const int* __restrict__ counts,
                                                      int* __restrict__ bsum) {
    __shared__ int wsum[4];
    const int tid = threadIdx.x;
    const int idx = blockIdx.x * 256 + tid;
    int x = (idx < N_NODES) ? counts[idx] : 0;
    #pragma unroll
    for (int off = 32; off >= 1; off >>= 1) x += __shfl_down(x, off, 64);
    if ((tid & 63) == 0) wsum[tid >> 6] = x;
    __syncthreads();
    if (tid == 0) bsum[blockIdx.x] = wsum[0] + wsum[1] + wsum[2] + wsum[3];
}

__global__ void prefix2_kernel(const int* __restrict__ bsum,
                               int* __restrict__ boff,
                               int* __restrict__ start) {
    const int lane = threadIdx.x;   // 64 threads
    const int v = (lane < NPB) ? bsum[lane] : 0;
    int x = v;
    #pragma unroll
    for (int off = 1; off < 64; off <<= 1) {
        int t = __shfl_up(x, off, 64);
        if (lane >= off) x += t;
    }
    if (lane < NPB) boff[lane] = x - v;      // exclusive
    if (lane == 0) start[N_NODES] = N_EDGES;
}

__global__ __launch_bounds__(256) void prefix3_kernel(const int* __restrict__ counts,
                                                      const int* __restrict__ boff,
                                                      int* __restrict__ start,
                                                      int* __restrict__ cursor) {
    __shared__ int wsum[4];
    const int tid  = threadIdx.x;
    const int idx  = blockIdx.x * 256 + tid;
    const int lane = tid & 63;
    const int wave = tid >> 6;
    const int v = (idx < N_NODES) ? counts[idx] : 0;
    int x = v;
    #pragma unroll
    for (int off = 1; off < 64; off <<= 1) {
        int t = __shfl_up(x, off, 64);
        if (lane >= off) x += t;
    }
    if (lane == 63) wsum[wave] = x;
    __syncthreads();
    int woff = 0;
    #pragma unroll
    for (int k = 0; k < 3; ++k) woff += (k < wave) ? wsum[k] : 0;
    const int excl = boff[blockIdx.x] + woff + x - v;
    if (idx < N_NODES) { start[idx] = excl; cursor[idx] = excl; }
}

// --- bucket edge ids by receiver ------------------------------------------
__global__ void reorder_kernel(const int4* __restrict__ recv4,
                               int* __restrict__ cursor,
                               int* __restrict__ sorted_eid) {
    int i = blockIdx.x * blockDim.x + threadIdx.x;
    if (i < N_EDGES / 4) {
        const int4 r = recv4[i];
        const int e = i * 4;
        sorted_eid[atomicAdd(&cursor[r.x], 1)] = e + 0;
        sorted_eid[atomicAdd(&cursor[r.y], 1)] = e + 1;
        sorted_eid[atomicAdd(&cursor[r.z], 1)] = e + 2;
        sorted_eid[atomicAdd(&cursor[r.w], 1)] = e + 3;
    }
}

// --- gather-sum: one 512-thread block per node, 16 row groups of 32 lanes --
// Lane reads float4 chunk l (16 B) of each row; next index prefetched before
// the current row load is consumed -> 2-deep pipeline. No atomics.
#define GW 16
__global__ __launch_bounds__(512) void gather_kernel(
        const float4* __restrict__ edge_feat4,
        const int* __restrict__ sorted_eid,
        const int* __restrict__ start,
        float4* __restrict__ agg4) {
    __shared__ float4 red[GW][32];             // 8 KB
    const int n   = blockIdx.x;
    const int tid = threadIdx.x;
    const int l   = tid & 31;
    const int w   = tid >> 5;
    const int s = start[n];
    const int e = start[n + 1];
    float4 acc = {0.f, 0.f, 0.f, 0.f};
    int i = s + w;
    if (i < e) {
        int eid = sorted_eid[i];
        while (true) {
            const int inext = i + GW;
            const int eid_next = (inext < e) ? sorted_eid[inext] : 0;  // prefetch
            const float4 v = edge_feat4[(long)eid * 32 + l];
            acc.x += v.x; acc.y += v.y; acc.z += v.z; acc.w += v.w;
            i = inext;
            if (i >= e) break;
            eid = eid_next;
        }
    }
    red[w][l] = acc;
    __syncthreads();
    if (w == 0) {
        float4 r = red[0][l];
        #pragma unroll
        for (int g = 1; g < GW; ++g) {
            const float4 t = red[g][l];
            r.x += t.x; r.y += t.y; r.z += t.z; r.w += t.w;
        }
        agg4[(long)n * 32 + l] = r;
    }
}

// --- register-tiled GEMM: out[10000,128] = [node||agg][10000,256] @ W + b --
// BM=64 BN=64 BK=32; 256 threads (16x16), 4x4 acc each. A staged k-major.
__global__ __launch_bounds__(256) void gemm_kernel(
        const float* __restrict__ node_feat,
        const float* __restrict__ agg,
        const float* __restrict__ W,
        const float* __restrict__ b,
        float* __restrict__ out) {
    __shared__ __align__(16) float As[32][68];  // k-major, stride 68 keeps 16B align, breaks bank stride
    __shared__ __align__(16) float Bs[32][64];
    const int tid = threadIdx.x;
    const int tx = tid & 15;
    const int ty = tid >> 4;
    const int m0 = blockIdx.x * 64;
    const int n0 = blockIdx.y * 64;

    float acc[4][4] = {};

    for (int kt = 0; kt < 2 * D_FEAT; kt += 32) {
        const float* src = (kt < D_FEAT) ? (node_feat + kt) : (agg + (kt - D_FEAT));
        {   // A tile: 64 rows x 32 cols -> As[k][m]
            const int r  = tid >> 3;          // 0..31
            const int c4 = tid & 7;           // float4 col group
            #pragma unroll
            for (int p = 0; p < 2; ++p) {
                int row = m0 + p * 32 + r;
                row = (row < N_NODES) ? row : (N_NODES - 1);
                const float4 a4 = *(const float4*)(src + (long)row * D_FEAT + c4 * 4);
                As[c4 * 4 + 0][p * 32 + r] = a4.x;
                As[c4 * 4 + 1][p * 32 + r] = a4.y;
                As[c4 * 4 + 2][p * 32 + r] = a4.z;
                As[c4 * 4 + 3][p * 32 + r] = a4.w;
            }
        }
        {   // B tile: 32 rows x 64 cols -> Bs[k][n]
            const int r  = tid >> 4;          // 0..15
            const int c4 = tid & 15;
            #pragma unroll
            for (int p = 0; p < 2; ++p) {
                const int row = kt + p * 16 + r;
                *(float4*)&Bs[p * 16 + r][c4 * 4] =
                    *(const float4*)(W + (long)row * D_FEAT + n0 + c4 * 4);
            }
        }
        __syncthreads();
        #pragma unroll
        for (int kk = 0; kk < 32; ++kk) {
            const float4 a4 = *(const float4*)&As[kk][ty * 4];
            const float4 b4 = *(const float4*)&Bs[kk][tx * 4];
            acc[0][0] += a4.x * b4.x; acc[0][1] += a4.x * b4.y;
            acc[0][2] += a4.x * b4.z; acc[0][3] += a4.x * b4.w;
            acc[1][0] += a4.y * b4.x; acc[1][1] += a4.y * b4.y;
            acc[1][2] += a4.y * b4.z; acc[1][3] += a4.y * b4.w;
            acc[2][0] += a4.z * b4.x; acc[2][1] += a4.z * b4.y;
            acc[2][2] += a4.z * b4.z; acc[2][3] += a4.z * b4.w;
            acc[3][0] += a4.w * b4.x; acc[3][1] += a4.w * b4.y;
            acc[3][2] += a4.w * b4.z; acc[3][3] += a4.w * b4.w;
        }
        __syncthreads();
    }

    const float4 bias = *(const float4*)(b + n0 + tx * 4);
    #pragma unroll
    for (int i2 = 0; i2 < 4; ++i2) {
        const int row = m0 + ty * 4 + i2;
        if (row < N_NODES) {
            float4 o;
            o.x = acc[i2][0] + bias.x;
            o.y = acc[i2][1] + bias.y;
            o.z = acc[i2][2] + bias.z;
            o.w = acc[i2][3] + bias.w;
            *(float4*)(out + (long)row * D_FEAT + n0 + tx * 4) = o;
        }
    }
}

// ---------------------------------------------------------------------------
extern "C" void kernel_launch(void* const* d_in, const int* in_sizes, int n_in,
                              void* d_out, int out_size, void* d_ws, size_t ws_size,
                              hipStream_t stream) {
    const float* edge_feat = (const float*)d_in[0];
    const float* node_feat = (const float*)d_in[1];
    const int*   recv      = (const int*)d_in[2];
    const float* W         = (const float*)d_in[3];
    const float* b         = (const float*)d_in[4];
    float* out = (float*)d_out;

    int* wsi    = (int*)d_ws;
    int* counts = wsi + WS_COUNTS;
    int* bsum   = wsi + WS_BSUM;
    int* boff   = wsi + WS_BOFF;
    int* startp = wsi + WS_START;
    int* cursor = wsi + WS_CURSOR;
    int* sorted = wsi + WS_SORTED;
    float* agg  = (float*)(wsi + WS_AGG);

    zero_counts_kernel<<<(N_NODES + 255) / 256, 256, 0, stream>>>(counts);
    hist_kernel<<<N_EDGES / 4 / 256, 256, 0, stream>>>((const int4*)recv, counts);
    prefix1_kernel<<<NPB, 256, 0, stream>>>(counts, bsum);
    prefix2_kernel<<<1, 64, 0, stream>>>(bsum, boff, startp);
    prefix3_kernel<<<NPB, 256, 0, stream>>>(counts, boff, startp, cursor);
    reorder_kernel<<<N_EDGES / 4 / 256, 256, 0, stream>>>((const int4*)recv, cursor, sorted);
    gather_kernel<<<N_NODES, 512, 0, stream>>>(
        (const float4*)edge_feat, sorted, startp, (float4*)agg);
    dim3 ggrid((N_NODES + 63) / 64, D_FEAT / 64);
    gemm_kernel<<<ggrid, 256, 0, stream>>>(node_feat, agg, W, b, out);
}